// Round 1
// baseline (568.797 us; speedup 1.0000x reference)
//
#include <hip/hip_runtime.h>

#define N_PIX   (32 * 64 * 64)          // 131072 rows
#define E_DIM   64
#define N_E     1024
#define Z_ELEMS (N_PIX * E_DIM)         // 8388608

#define LOSS_OFF 0
#define ZQ_OFF   1
#define PERP_OFF (1 + Z_ELEMS)                          // 8388609
#define ENC_OFF  ((size_t)(2 + Z_ELEMS))                // 8388610
#define IDX_OFF  (ENC_OFF + (size_t)N_PIX * N_E)        // 142606338

// ---- precompute ||e||^2 per codebook row ----
__global__ void vq_prep(const float* __restrict__ emb, float* __restrict__ ee) {
    int e = blockIdx.x * blockDim.x + threadIdx.x;
    if (e < N_E) {
        const float* r = emb + e * E_DIM;
        float s0 = 0.f, s1 = 0.f, s2 = 0.f, s3 = 0.f;
        #pragma unroll
        for (int c = 0; c < E_DIM; c += 4) {
            s0 = fmaf(r[c],     r[c],     s0);
            s1 = fmaf(r[c + 1], r[c + 1], s1);
            s2 = fmaf(r[c + 2], r[c + 2], s2);
            s3 = fmaf(r[c + 3], r[c + 3], s3);
        }
        ee[e] = (s0 + s1) + (s2 + s3);
    }
}

// ---- main: argmin, z_q, one-hot, indices, loss partial, histogram ----
__global__ __launch_bounds__(256) void vq_main(
    const float* __restrict__ z, const float* __restrict__ emb,
    const float* __restrict__ ee, float* __restrict__ out,
    unsigned* __restrict__ counts, double* __restrict__ loss_acc)
{
    const int tid = threadIdx.x;
    const int p   = blockIdx.x * 256 + tid;   // pixel row, = b*4096 + h*64 + w
    const int b   = p >> 12;
    const int hw  = p & 4095;

    // gather z row across channels (stride 4096 floats; coalesced across lanes)
    const float* zp = z + (size_t)b * (64 * 4096) + hw;
    float zv[E_DIM];
    #pragma unroll
    for (int c = 0; c < E_DIM; ++c) zv[c] = zp[(size_t)c * 4096];

    float s0 = 0.f, s1 = 0.f, s2 = 0.f, s3 = 0.f;
    #pragma unroll
    for (int c = 0; c < E_DIM; c += 4) {
        s0 = fmaf(zv[c],     zv[c],     s0);
        s1 = fmaf(zv[c + 1], zv[c + 1], s1);
        s2 = fmaf(zv[c + 2], zv[c + 2], s2);
        s3 = fmaf(zv[c + 3], zv[c + 3], s3);
    }
    const float zz = (s0 + s1) + (s2 + s3);

    float dmin = 3.4e38f;
    int   best = 0;
    for (int e = 0; e < N_E; ++e) {
        const float* er = emb + e * E_DIM;   // wave-uniform -> s_load
        float d0 = 0.f, d1 = 0.f, d2 = 0.f, d3 = 0.f;
        #pragma unroll
        for (int c = 0; c < E_DIM; c += 4) {
            d0 = fmaf(zv[c],     er[c],     d0);
            d1 = fmaf(zv[c + 1], er[c + 1], d1);
            d2 = fmaf(zv[c + 2], er[c + 2], d2);
            d3 = fmaf(zv[c + 3], er[c + 3], d3);
        }
        const float dot = (d0 + d1) + (d2 + d3);
        const float d   = zz + ee[e] - 2.0f * dot;
        if (d < dmin) { dmin = d; best = e; }   // strict < keeps first (argmin tie-break)
    }

    // indices (as f32 values) + histogram
    out[IDX_OFF + p] = (float)best;
    atomicAdd(&counts[best], 1u);

    // z_q (NCHW scatter, coalesced across lanes) + loss partial
    const float* eb = emb + best * E_DIM;   // per-lane divergent; L2-resident
    float l0 = 0.f, l1 = 0.f, l2 = 0.f, l3 = 0.f;
    #pragma unroll
    for (int c = 0; c < E_DIM; c += 4) {
        const float q0 = eb[c], q1 = eb[c + 1], q2 = eb[c + 2], q3 = eb[c + 3];
        out[ZQ_OFF + (size_t)(b * 64 + c    ) * 4096 + hw] = q0;
        out[ZQ_OFF + (size_t)(b * 64 + c + 1) * 4096 + hw] = q1;
        out[ZQ_OFF + (size_t)(b * 64 + c + 2) * 4096 + hw] = q2;
        out[ZQ_OFF + (size_t)(b * 64 + c + 3) * 4096 + hw] = q3;
        const float t0 = q0 - zv[c],     t1 = q1 - zv[c + 1];
        const float t2 = q2 - zv[c + 2], t3 = q3 - zv[c + 3];
        l0 = fmaf(t0, t0, l0); l1 = fmaf(t1, t1, l1);
        l2 = fmaf(t2, t2, l2); l3 = fmaf(t3, t3, l3);
    }
    float lsum = (l0 + l1) + (l2 + l3);
    #pragma unroll
    for (int o = 32; o > 0; o >>= 1) lsum += __shfl_down(lsum, o);
    if ((tid & 63) == 0) atomicAdd(loss_acc, (double)lsum);

    // one-hot: block writes its 256 rows cooperatively, fully coalesced.
    // ENC_OFF % 4 == 2 elements -> 16B-misaligned; use two float2 (8B-aligned) stores.
    __shared__ int sbest[256];
    sbest[tid] = best;
    __syncthreads();
    const size_t blockbase = ENC_OFF + (size_t)blockIdx.x * 256 * N_E;
    const int col = tid * 4;
    for (int r = 0; r < 256; ++r) {
        const int rb = sbest[r];
        float2 v0 = make_float2(rb == col     ? 1.f : 0.f, rb == col + 1 ? 1.f : 0.f);
        float2 v1 = make_float2(rb == col + 2 ? 1.f : 0.f, rb == col + 3 ? 1.f : 0.f);
        float2* dst = (float2*)(out + blockbase + (size_t)r * N_E + col);
        dst[0] = v0;
        dst[1] = v1;
    }
}

// ---- finalize: perplexity + loss ----
__global__ void vq_final(const unsigned* __restrict__ counts,
                         const double* __restrict__ loss_acc,
                         float* __restrict__ out)
{
    __shared__ float red[N_E];
    const int e = threadIdx.x;
    const float em   = (float)counts[e] * (1.0f / (float)N_PIX);
    red[e] = em * logf(em + 1e-10f);
    __syncthreads();
    for (int s = 512; s > 0; s >>= 1) {
        if (e < s) red[e] += red[e + s];
        __syncthreads();
    }
    if (e == 0) {
        out[PERP_OFF] = expf(-red[0]);
        out[LOSS_OFF] = (float)((*loss_acc) * (1.25 / (double)Z_ELEMS));
    }
}

extern "C" void kernel_launch(void* const* d_in, const int* in_sizes, int n_in,
                              void* d_out, int out_size, void* d_ws, size_t ws_size,
                              hipStream_t stream) {
    const float* z   = (const float*)d_in[0];
    const float* emb = (const float*)d_in[1];
    float* out = (float*)d_out;

    unsigned* counts   = (unsigned*)d_ws;                   // 4096 B
    double*   loss_acc = (double*)((char*)d_ws + 4096);     // 8 B
    float*    ee       = (float*)((char*)d_ws + 8192);      // 4096 B

    hipMemsetAsync(d_ws, 0, 4104, stream);
    vq_prep<<<4, 256, 0, stream>>>(emb, ee);
    vq_main<<<N_PIX / 256, 256, 0, stream>>>(z, emb, ee, out, counts, loss_acc);
    vq_final<<<1, N_E, 0, stream>>>(counts, loss_acc, out);
}

// Round 3
// 535.645 us; speedup vs baseline: 1.0619x; 1.0619x over previous
//
#include <hip/hip_runtime.h>

#define N_PIX   (32 * 64 * 64)          // 131072 rows
#define E_DIM   64
#define N_E     1024
#define Z_ELEMS (N_PIX * E_DIM)         // 8388608

#define LOSS_OFF 0
#define ZQ_OFF   1
#define PERP_OFF (1 + Z_ELEMS)                          // 8388609
#define ENC_OFF  ((size_t)(2 + Z_ELEMS))                // 8388610
#define IDX_OFF  (ENC_OFF + (size_t)N_PIX * N_E)        // 142606338

typedef float f32x2 __attribute__((ext_vector_type(2)));

// ---- precompute ||e||^2 per codebook row ----
__global__ void vq_prep(const float* __restrict__ emb, float* __restrict__ ee) {
    int e = blockIdx.x * blockDim.x + threadIdx.x;
    if (e < N_E) {
        const float* r = emb + e * E_DIM;
        float s0 = 0.f, s1 = 0.f, s2 = 0.f, s3 = 0.f;
        #pragma unroll
        for (int c = 0; c < E_DIM; c += 4) {
            s0 = fmaf(r[c],     r[c],     s0);
            s1 = fmaf(r[c + 1], r[c + 1], s1);
            s2 = fmaf(r[c + 2], r[c + 2], s2);
            s3 = fmaf(r[c + 3], r[c + 3], s3);
        }
        ee[e] = (s0 + s1) + (s2 + s3);
    }
}

// ---- main: argmin, z_q, one-hot, indices, loss partial, histogram ----
// min_waves_per_EU = 2: grid is 512 blocks = 2048 waves = 2 waves/SIMD resident,
// so allow the allocator up to 128 VGPRs -> zv[64] stays in registers and the
// inner loop is pure v_fmac_f32(vdst, s_emb, v_z) with scalar-prefetched emb.
__global__ __launch_bounds__(256, 2) void vq_main(
    const float* __restrict__ z, const float* __restrict__ emb,
    const float* __restrict__ ee, float* __restrict__ out,
    unsigned* __restrict__ counts, double* __restrict__ loss_acc)
{
    const int tid = threadIdx.x;
    const int p   = blockIdx.x * 256 + tid;   // pixel row, = b*4096 + h*64 + w
    const int b   = p >> 12;
    const int hw  = p & 4095;

    // gather z row across channels (stride 4096 floats; coalesced across lanes)
    const float* zp = z + (size_t)b * (64 * 4096) + hw;
    float zv[E_DIM];
    #pragma unroll
    for (int c = 0; c < E_DIM; ++c) zv[c] = zp[(size_t)c * 4096];

    float s0 = 0.f, s1 = 0.f, s2 = 0.f, s3 = 0.f;
    #pragma unroll
    for (int c = 0; c < E_DIM; c += 4) {
        s0 = fmaf(zv[c],     zv[c],     s0);
        s1 = fmaf(zv[c + 1], zv[c + 1], s1);
        s2 = fmaf(zv[c + 2], zv[c + 2], s2);
        s3 = fmaf(zv[c + 3], zv[c + 3], s3);
    }
    const float zz = (s0 + s1) + (s2 + s3);

    float dmin = 3.4e38f;
    int   best = 0;
    for (int e = 0; e < N_E; ++e) {
        const float* er = emb + e * E_DIM;   // wave-uniform -> s_load_dwordx16
        float d0 = 0.f, d1 = 0.f, d2 = 0.f, d3 = 0.f;
        #pragma unroll
        for (int c = 0; c < E_DIM; c += 4) {
            d0 = fmaf(zv[c],     er[c],     d0);
            d1 = fmaf(zv[c + 1], er[c + 1], d1);
            d2 = fmaf(zv[c + 2], er[c + 2], d2);
            d3 = fmaf(zv[c + 3], er[c + 3], d3);
        }
        const float dot = (d0 + d1) + (d2 + d3);
        const float d   = zz + ee[e] - 2.0f * dot;
        if (d < dmin) { dmin = d; best = e; }   // strict < keeps first (argmin tie-break)
    }

    // indices (as f32 values) + histogram
    out[IDX_OFF + p] = (float)best;
    atomicAdd(&counts[best], 1u);

    // z_q (NCHW scatter, coalesced across lanes) + loss partial
    const float* eb = emb + best * E_DIM;   // per-lane divergent; L2-resident
    float l0 = 0.f, l1 = 0.f, l2 = 0.f, l3 = 0.f;
    #pragma unroll
    for (int c = 0; c < E_DIM; c += 4) {
        const float q0 = eb[c], q1 = eb[c + 1], q2 = eb[c + 2], q3 = eb[c + 3];
        __builtin_nontemporal_store(q0, &out[ZQ_OFF + (size_t)(b * 64 + c    ) * 4096 + hw]);
        __builtin_nontemporal_store(q1, &out[ZQ_OFF + (size_t)(b * 64 + c + 1) * 4096 + hw]);
        __builtin_nontemporal_store(q2, &out[ZQ_OFF + (size_t)(b * 64 + c + 2) * 4096 + hw]);
        __builtin_nontemporal_store(q3, &out[ZQ_OFF + (size_t)(b * 64 + c + 3) * 4096 + hw]);
        const float t0 = q0 - zv[c],     t1 = q1 - zv[c + 1];
        const float t2 = q2 - zv[c + 2], t3 = q3 - zv[c + 3];
        l0 = fmaf(t0, t0, l0); l1 = fmaf(t1, t1, l1);
        l2 = fmaf(t2, t2, l2); l3 = fmaf(t3, t3, l3);
    }
    float lsum = (l0 + l1) + (l2 + l3);
    #pragma unroll
    for (int o = 32; o > 0; o >>= 1) lsum += __shfl_down(lsum, o);
    if ((tid & 63) == 0) atomicAdd(loss_acc, (double)lsum);

    // one-hot: block writes its 256 rows cooperatively, fully coalesced.
    // ENC_OFF % 4 == 2 elements -> 16B-misaligned; use two f32x2 (8B-aligned)
    // non-temporal stores (512 MB stream, never re-read -> don't pollute L2).
    __shared__ int sbest[256];
    sbest[tid] = best;
    __syncthreads();
    const size_t blockbase = ENC_OFF + (size_t)blockIdx.x * 256 * N_E;
    const int col = tid * 4;
    for (int r = 0; r < 256; ++r) {
        const int rb = sbest[r];
        f32x2 v0 = { rb == col     ? 1.f : 0.f, rb == col + 1 ? 1.f : 0.f };
        f32x2 v1 = { rb == col + 2 ? 1.f : 0.f, rb == col + 3 ? 1.f : 0.f };
        f32x2* dst = (f32x2*)(out + blockbase + (size_t)r * N_E + col);
        __builtin_nontemporal_store(v0, &dst[0]);
        __builtin_nontemporal_store(v1, &dst[1]);
    }
}

// ---- finalize: perplexity + loss ----
__global__ void vq_final(const unsigned* __restrict__ counts,
                         const double* __restrict__ loss_acc,
                         float* __restrict__ out)
{
    __shared__ float red[N_E];
    const int e = threadIdx.x;
    const float em   = (float)counts[e] * (1.0f / (float)N_PIX);
    red[e] = em * logf(em + 1e-10f);
    __syncthreads();
    for (int s = 512; s > 0; s >>= 1) {
        if (e < s) red[e] += red[e + s];
        __syncthreads();
    }
    if (e == 0) {
        out[PERP_OFF] = expf(-red[0]);
        out[LOSS_OFF] = (float)((*loss_acc) * (1.25 / (double)Z_ELEMS));
    }
}

extern "C" void kernel_launch(void* const* d_in, const int* in_sizes, int n_in,
                              void* d_out, int out_size, void* d_ws, size_t ws_size,
                              hipStream_t stream) {
    const float* z   = (const float*)d_in[0];
    const float* emb = (const float*)d_in[1];
    float* out = (float*)d_out;

    unsigned* counts   = (unsigned*)d_ws;                   // 4096 B
    double*   loss_acc = (double*)((char*)d_ws + 4096);     // 8 B
    float*    ee       = (float*)((char*)d_ws + 8192);      // 4096 B

    (void)hipMemsetAsync(d_ws, 0, 4104, stream);
    vq_prep<<<4, 256, 0, stream>>>(emb, ee);
    vq_main<<<N_PIX / 256, 256, 0, stream>>>(z, emb, ee, out, counts, loss_acc);
    vq_final<<<1, N_E, 0, stream>>>(counts, loss_acc, out);
}